// Round 1
// baseline (414.357 us; speedup 1.0000x reference)
//
#include <hip/hip_runtime.h>
#include <hip/hip_bf16.h>

// Problem: out[b,j] = sum_{i,k} coef[j,i,k] * tanh(x[b,i])^k
// B=8192, IN=1024, OUT=1024, ORDER=7  ->  GEMM M=8192, N=1024, K=8192 (bf16 MFMA)
// A[b, i*8+k] = t[b,i]^k computed on the fly; Bt = coef flat [1024, 8192] (NT GEMM).

#define BM 128
#define BN 128
#define BK 64
#define LDK 72   // padded LDS K-stride (bf16 elems): 144 B row stride, 16B aligned, bank-rotating

typedef short bf16x8 __attribute__((ext_vector_type(8)));
typedef short bf16x4 __attribute__((ext_vector_type(4)));
typedef float f32x4  __attribute__((ext_vector_type(4)));

__device__ __forceinline__ unsigned short f2bf(float f) {
    union { float f; unsigned u; } v; v.f = f;
    unsigned r = v.u + 0x7fffu + ((v.u >> 16) & 1u);   // round-to-nearest-even
    return (unsigned short)(r >> 16);
}

__global__ __launch_bounds__(256, 2)
void taylor_gemm(const float* __restrict__ x, const float* __restrict__ trp,
                 const float* __restrict__ coef, float* __restrict__ out)
{
    __shared__ unsigned short As[BM * LDK];
    __shared__ unsigned short Bs[BN * LDK];

    const int t  = threadIdx.x;
    const int m0 = blockIdx.x * BM;
    const int n0 = blockIdx.y * BN;
    const float tr = trp[0];

    const int w    = t >> 6;           // wave 0..3
    const int lane = t & 63;
    const int wm   = (w >> 1) * 64;    // wave m-offset in tile
    const int wn   = (w & 1) * 64;     // wave n-offset in tile
    const int lrow = lane & 15;        // A/B operand row (m or n)
    const int kq   = (lane >> 4) * 8;  // k sub-offset per quad

    f32x4 acc[4][4];
    #pragma unroll
    for (int i = 0; i < 4; i++)
        #pragma unroll
        for (int j = 0; j < 4; j++)
            acc[i][j] = (f32x4){0.f, 0.f, 0.f, 0.f};

    // staging thread mapping
    const int bcol  = t & 15;          // float4 column (B tile: 64 floats = 16 float4 per row)
    const int brow0 = t >> 4;          // 0..15, step 16 -> 128 rows
    const int acol  = t & 7;           // x column within group of 8
    const int arow0 = t >> 3;          // 0..31, step 32 -> 128 rows

    for (int k0 = 0; k0 < 8192; k0 += BK) {
        const int i0 = k0 >> 3;        // x column base (each x col spans 8 K slots)

        // ---- stage B: coef fp32 -> bf16 ----
        #pragma unroll
        for (int r = 0; r < 8; ++r) {
            const int row = brow0 + r * 16;
            const float4 v = *(const float4*)(coef + (size_t)(n0 + row) * 8192 + k0 + bcol * 4);
            bf16x4 pk;
            pk[0] = (short)f2bf(v.x); pk[1] = (short)f2bf(v.y);
            pk[2] = (short)f2bf(v.z); pk[3] = (short)f2bf(v.w);
            *(bf16x4*)&Bs[row * LDK + bcol * 4] = pk;   // 8B aligned
        }

        // ---- stage A: tanh powers -> bf16 ----
        #pragma unroll
        for (int r = 0; r < 4; ++r) {
            const int row = arow0 + r * 32;
            const float xv = x[(size_t)(m0 + row) * 1024 + i0 + acol];
            const float e  = __expf(2.0f * tr * xv);
            const float tt = 1.0f - 2.0f / (e + 1.0f);  // tanh(tr*x), stable both tails
            bf16x8 pk;
            float p = 1.0f;
            #pragma unroll
            for (int k = 0; k < 8; ++k) { pk[k] = (short)f2bf(p); p *= tt; }
            *(bf16x8*)&As[row * LDK + acol * 8] = pk;   // 16B aligned
        }

        __syncthreads();

        // ---- compute: 2 k-steps x 16 MFMAs per wave ----
        #pragma unroll
        for (int kk = 0; kk < BK; kk += 32) {
            bf16x8 a[4], b[4];
            #pragma unroll
            for (int i = 0; i < 4; i++)
                a[i] = *(const bf16x8*)&As[(wm + i * 16 + lrow) * LDK + kk + kq];
            #pragma unroll
            for (int j = 0; j < 4; j++)
                b[j] = *(const bf16x8*)&Bs[(wn + j * 16 + lrow) * LDK + kk + kq];
            #pragma unroll
            for (int i = 0; i < 4; i++)
                #pragma unroll
                for (int j = 0; j < 4; j++)
                    acc[i][j] = __builtin_amdgcn_mfma_f32_16x16x32_bf16(a[i], b[j], acc[i][j], 0, 0, 0);
        }

        __syncthreads();
    }

    // ---- epilogue: C/D layout col=lane&15, row=(lane>>4)*4+reg ----
    const int crow = (lane >> 4) * 4;
    const int ccol = lane & 15;
    #pragma unroll
    for (int i = 0; i < 4; i++) {
        #pragma unroll
        for (int j = 0; j < 4; j++) {
            const int m = m0 + wm + i * 16 + crow;
            const int n = n0 + wn + j * 16 + ccol;
            #pragma unroll
            for (int r = 0; r < 4; ++r)
                out[(size_t)(m + r) * 1024 + n] = acc[i][j][r];
        }
    }
}

extern "C" void kernel_launch(void* const* d_in, const int* in_sizes, int n_in,
                              void* d_out, int out_size, void* d_ws, size_t ws_size,
                              hipStream_t stream) {
    const float* x    = (const float*)d_in[0];
    const float* trp  = (const float*)d_in[1];
    const float* coef = (const float*)d_in[2];
    float* out = (float*)d_out;

    dim3 grid(8192 / BM, 1024 / BN);   // 64 x 8 = 512 blocks -> 2 blocks/CU
    dim3 block(256);
    taylor_gemm<<<grid, block, 0, stream>>>(x, trp, coef, out);
}

// Round 2
// 295.418 us; speedup vs baseline: 1.4026x; 1.4026x over previous
//
#include <hip/hip_runtime.h>
#include <hip/hip_bf16.h>

// out[b,j] = sum_{i,k} coef[j,i,k] * tanh(x[b,i])^k
// B=8192, IN=1024, OUT=1024, ORDER=7 -> GEMM M=8192, N=1024, K=8192 bf16 MFMA.
// 3-pass: (1) coef fp32->bf16, (2) A = tanh-powers bf16 [8192x8192], (3) m97-style NT GEMM.
// Falls back to the round-1 fused kernel if ws_size < 144 MiB.

#define BM 128
#define BN 128
#define BK 64
#define KDIM 8192

typedef short bf16x8 __attribute__((ext_vector_type(8)));
typedef short bf16x4 __attribute__((ext_vector_type(4)));
typedef float f32x4  __attribute__((ext_vector_type(4)));

__device__ __forceinline__ unsigned short f2bf(float f) {
    union { float f; unsigned u; } v; v.f = f;
    unsigned r = v.u + 0x7fffu + ((v.u >> 16) & 1u);   // RTE
    return (unsigned short)(r >> 16);
}

__device__ __forceinline__ void gload_lds16(const void* gp, void* lp) {
    __builtin_amdgcn_global_load_lds(
        (const __attribute__((address_space(1))) void*)gp,
        (__attribute__((address_space(3))) void*)lp, 16, 0, 0);
}

// ---- pass 1: coef fp32 -> bf16 ----
__global__ __launch_bounds__(256)
void cvt_coef(const float4* __restrict__ src, bf16x4* __restrict__ dst) {
    const int i = blockIdx.x * 256 + threadIdx.x;
    const float4 v = src[i];
    bf16x4 p;
    p[0] = (short)f2bf(v.x); p[1] = (short)f2bf(v.y);
    p[2] = (short)f2bf(v.z); p[3] = (short)f2bf(v.w);
    dst[i] = p;
}

// ---- pass 2: A[b, i*8+k] = tanh(x[b,i])^k, bf16 ----
__global__ __launch_bounds__(256)
void tanh_pow(const float* __restrict__ x, const float* __restrict__ trp,
              bf16x8* __restrict__ A) {
    const int i = blockIdx.x * 256 + threadIdx.x;
    const float tr = trp[0];
    const float xv = x[i];
    const float e  = __expf(2.0f * tr * xv);
    const float tt = 1.0f - 2.0f / (e + 1.0f);
    bf16x8 pk;
    float p = 1.0f;
    #pragma unroll
    for (int k = 0; k < 8; ++k) { pk[k] = (short)f2bf(p); p *= tt; }
    A[i] = pk;   // 16B store, contiguous across lanes
}

// ---- pass 3: NT GEMM, m97 structure ----
__global__ __launch_bounds__(256, 2)
void gemm_bt(const unsigned short* __restrict__ A, const unsigned short* __restrict__ Bt,
             float* __restrict__ out)
{
    __shared__ unsigned short As[BM * BK];   // 16 KB, unpadded (global_load_lds layout)
    __shared__ unsigned short Bs[BN * BK];   // 16 KB

    const int t    = threadIdx.x;
    const int m0   = blockIdx.x * BM;
    const int n0   = blockIdx.y * BN;
    const int w    = t >> 6;
    const int lane = t & 63;
    const int wm   = (w >> 1) * 64;
    const int wn   = (w & 1) * 64;
    const int lrow = lane & 15;
    const int kq   = (lane >> 4) * 8;

    // staging map: thread t covers row = r*32 + (t>>3), col = (t&7)*8 (bf16)
    const int srow = t >> 3;
    const int scol = (t & 7) * 8;
    const int wbase = w * 512;               // wave-uniform LDS base (ushort elems) per round

    f32x4 acc[4][4];
    #pragma unroll
    for (int i = 0; i < 4; i++)
        #pragma unroll
        for (int j = 0; j < 4; j++)
            acc[i][j] = (f32x4){0.f, 0.f, 0.f, 0.f};

    const size_t abase = (size_t)(m0 + srow) * KDIM + scol;
    const size_t bbase = (size_t)(n0 + srow) * KDIM + scol;

    for (int k0 = 0; k0 < KDIM; k0 += BK) {
        #pragma unroll
        for (int r = 0; r < 4; ++r)
            gload_lds16(A + abase + (size_t)r * 32 * KDIM + k0, &As[r * 2048 + wbase]);
        #pragma unroll
        for (int r = 0; r < 4; ++r)
            gload_lds16(Bt + bbase + (size_t)r * 32 * KDIM + k0, &Bs[r * 2048 + wbase]);

        __syncthreads();

        #pragma unroll
        for (int kk = 0; kk < BK; kk += 32) {
            bf16x8 a[4], b[4];
            #pragma unroll
            for (int i = 0; i < 4; i++)
                a[i] = *(const bf16x8*)&As[(wm + i * 16 + lrow) * BK + kk + kq];
            #pragma unroll
            for (int j = 0; j < 4; j++)
                b[j] = *(const bf16x8*)&Bs[(wn + j * 16 + lrow) * BK + kk + kq];
            #pragma unroll
            for (int i = 0; i < 4; i++)
                #pragma unroll
                for (int j = 0; j < 4; j++)
                    acc[i][j] = __builtin_amdgcn_mfma_f32_16x16x32_bf16(a[i], b[j], acc[i][j], 0, 0, 0);
        }

        __syncthreads();
    }

    const int crow = (lane >> 4) * 4;
    const int ccol = lane & 15;
    #pragma unroll
    for (int i = 0; i < 4; i++) {
        #pragma unroll
        for (int j = 0; j < 4; j++) {
            const int m = m0 + wm + i * 16 + crow;
            const int n = n0 + wn + j * 16 + ccol;
            #pragma unroll
            for (int r = 0; r < 4; ++r)
                out[(size_t)(m + r) * 1024 + n] = acc[i][j][r];
        }
    }
}

// ---- fallback: round-1 fused kernel (used only if ws too small) ----
#define LDK 72
__global__ __launch_bounds__(256, 2)
void taylor_gemm(const float* __restrict__ x, const float* __restrict__ trp,
                 const float* __restrict__ coef, float* __restrict__ out)
{
    __shared__ unsigned short As[BM * LDK];
    __shared__ unsigned short Bs[BN * LDK];

    const int t  = threadIdx.x;
    const int m0 = blockIdx.x * BM;
    const int n0 = blockIdx.y * BN;
    const float tr = trp[0];

    const int w    = t >> 6;
    const int lane = t & 63;
    const int wm   = (w >> 1) * 64;
    const int wn   = (w & 1) * 64;
    const int lrow = lane & 15;
    const int kq   = (lane >> 4) * 8;

    f32x4 acc[4][4];
    #pragma unroll
    for (int i = 0; i < 4; i++)
        #pragma unroll
        for (int j = 0; j < 4; j++)
            acc[i][j] = (f32x4){0.f, 0.f, 0.f, 0.f};

    const int bcol  = t & 15;
    const int brow0 = t >> 4;
    const int acol  = t & 7;
    const int arow0 = t >> 3;

    for (int k0 = 0; k0 < KDIM; k0 += BK) {
        const int i0 = k0 >> 3;
        #pragma unroll
        for (int r = 0; r < 8; ++r) {
            const int row = brow0 + r * 16;
            const float4 v = *(const float4*)(coef + (size_t)(n0 + row) * KDIM + k0 + bcol * 4);
            bf16x4 pk;
            pk[0] = (short)f2bf(v.x); pk[1] = (short)f2bf(v.y);
            pk[2] = (short)f2bf(v.z); pk[3] = (short)f2bf(v.w);
            *(bf16x4*)&Bs[row * LDK + bcol * 4] = pk;
        }
        #pragma unroll
        for (int r = 0; r < 4; ++r) {
            const int row = arow0 + r * 32;
            const float xv = x[(size_t)(m0 + row) * 1024 + i0 + acol];
            const float e  = __expf(2.0f * tr * xv);
            const float tt = 1.0f - 2.0f / (e + 1.0f);
            bf16x8 pk;
            float p = 1.0f;
            #pragma unroll
            for (int k = 0; k < 8; ++k) { pk[k] = (short)f2bf(p); p *= tt; }
            *(bf16x8*)&As[row * LDK + acol * 8] = pk;
        }
        __syncthreads();
        #pragma unroll
        for (int kk = 0; kk < BK; kk += 32) {
            bf16x8 a[4], b[4];
            #pragma unroll
            for (int i = 0; i < 4; i++)
                a[i] = *(const bf16x8*)&As[(wm + i * 16 + lrow) * LDK + kk + kq];
            #pragma unroll
            for (int j = 0; j < 4; j++)
                b[j] = *(const bf16x8*)&Bs[(wn + j * 16 + lrow) * LDK + kk + kq];
            #pragma unroll
            for (int i = 0; i < 4; i++)
                #pragma unroll
                for (int j = 0; j < 4; j++)
                    acc[i][j] = __builtin_amdgcn_mfma_f32_16x16x32_bf16(a[i], b[j], acc[i][j], 0, 0, 0);
        }
        __syncthreads();
    }

    const int crow = (lane >> 4) * 4;
    const int ccol = lane & 15;
    #pragma unroll
    for (int i = 0; i < 4; i++) {
        #pragma unroll
        for (int j = 0; j < 4; j++) {
            const int m = m0 + wm + i * 16 + crow;
            const int n = n0 + wn + j * 16 + ccol;
            #pragma unroll
            for (int r = 0; r < 4; ++r)
                out[(size_t)(m + r) * 1024 + n] = acc[i][j][r];
        }
    }
}

extern "C" void kernel_launch(void* const* d_in, const int* in_sizes, int n_in,
                              void* d_out, int out_size, void* d_ws, size_t ws_size,
                              hipStream_t stream) {
    const float* x    = (const float*)d_in[0];
    const float* trp  = (const float*)d_in[1];
    const float* coef = (const float*)d_in[2];
    float* out = (float*)d_out;

    const size_t COEF_BYTES = (size_t)1024 * KDIM * 2;            // 16 MiB
    const size_t A_BYTES    = (size_t)8192 * KDIM * 2;            // 128 MiB
    dim3 block(256);

    if (ws_size >= COEF_BYTES + A_BYTES) {
        unsigned short* coef_bf = (unsigned short*)d_ws;
        unsigned short* A_bf    = (unsigned short*)((char*)d_ws + COEF_BYTES);

        cvt_coef<<<dim3((1024 * KDIM / 4) / 256), block, 0, stream>>>(
            (const float4*)coef, (bf16x4*)coef_bf);
        tanh_pow<<<dim3((8192 * 1024) / 256), block, 0, stream>>>(
            x, trp, (bf16x8*)A_bf);
        gemm_bt<<<dim3(8192 / BM, 1024 / BN), block, 0, stream>>>(
            A_bf, coef_bf, out);
    } else {
        taylor_gemm<<<dim3(8192 / BM, 1024 / BN), block, 0, stream>>>(x, trp, coef, out);
    }
}

// Round 3
// 248.143 us; speedup vs baseline: 1.6698x; 1.1905x over previous
//
#include <hip/hip_runtime.h>
#include <hip/hip_bf16.h>

// out[b,j] = sum_{i,k} coef[j,i,k] * tanh(x[b,i])^k
// B=8192, IN=1024, OUT=1024, ORDER=7 -> GEMM M=8192, N=1024, K=8192 bf16 MFMA.
// Passes: (1) prep: coef fp32->bf16 + A = tanh-powers bf16 [8192x8192];
//         (2) NT GEMM, m97 structure + XOR-swizzled LDS (kills 16-way bank conflicts
//             while keeping global_load_lds's fixed base+lane*16 LDS destinations).
// Falls back to the round-1 fused kernel if ws_size < 144 MiB.

#define BM 128
#define BN 128
#define BK 64
#define KDIM 8192

typedef short bf16x8 __attribute__((ext_vector_type(8)));
typedef short bf16x4 __attribute__((ext_vector_type(4)));
typedef float f32x4  __attribute__((ext_vector_type(4)));

__device__ __forceinline__ unsigned short f2bf(float f) {
    union { float f; unsigned u; } v; v.f = f;
    unsigned r = v.u + 0x7fffu + ((v.u >> 16) & 1u);   // RTE
    return (unsigned short)(r >> 16);
}

__device__ __forceinline__ void gload_lds16(const void* gp, void* lp) {
    __builtin_amdgcn_global_load_lds(
        (const __attribute__((address_space(1))) void*)gp,
        (__attribute__((address_space(3))) void*)lp, 16, 0, 0);
}

// ---- pass 1: coef fp32->bf16 (blocks [0,8192)) + tanh powers (blocks [8192,40960)) ----
#define COEF_BLOCKS 8192   // 8192*256 threads * 1 float4 = 8.4M floats
#define TANH_BLOCKS 32768  // 32768*256 threads * 1 x-val  = 8.4M x values

__global__ __launch_bounds__(256)
void prep(const float* __restrict__ x, const float* __restrict__ trp,
          const float4* __restrict__ coef, bf16x4* __restrict__ coef_bf,
          bf16x8* __restrict__ A) {
    const int b = blockIdx.x;
    if (b < COEF_BLOCKS) {
        const int i = b * 256 + threadIdx.x;
        const float4 v = coef[i];
        bf16x4 p;
        p[0] = (short)f2bf(v.x); p[1] = (short)f2bf(v.y);
        p[2] = (short)f2bf(v.z); p[3] = (short)f2bf(v.w);
        coef_bf[i] = p;
    } else {
        const int i = (b - COEF_BLOCKS) * 256 + threadIdx.x;
        const float tr = trp[0];
        const float xv = x[i];
        const float e  = __expf(2.0f * tr * xv);
        const float tt = 1.0f - 2.0f * __builtin_amdgcn_rcpf(e + 1.0f);  // tanh(tr*x)
        bf16x8 pk;
        float p = 1.0f;
        #pragma unroll
        for (int k = 0; k < 8; ++k) { pk[k] = (short)f2bf(p); p *= tt; }
        A[i] = pk;   // 16B store, contiguous across lanes
    }
}

// ---- pass 2: NT GEMM, m97 structure + XOR swizzle ----
// LDS row m (64 bf16 = 8 chunks of 16B): slot s holds global chunk s ^ (m&7).
__global__ __launch_bounds__(256, 2)
void gemm_bt(const unsigned short* __restrict__ A, const unsigned short* __restrict__ Bt,
             float* __restrict__ out)
{
    __shared__ unsigned short As[BM * BK];   // 16 KB
    __shared__ unsigned short Bs[BN * BK];   // 16 KB

    const int t    = threadIdx.x;
    const int m0   = blockIdx.x * BM;
    const int n0   = blockIdx.y * BN;
    const int w    = t >> 6;
    const int lane = t & 63;
    const int wm   = (w >> 1) * 64;
    const int wn   = (w & 1) * 64;
    const int lrow = lane & 15;

    // staging map: thread t covers row = r*32 + (t>>3); fetches SWIZZLED chunk
    // (t&7) ^ ((t>>3)&7) so that LDS slot (t&7) of row gets chunk slot^(row&7).
    const int srow   = t >> 3;
    const int schunk = (t & 7) ^ (srow & 7);
    const int wbase  = w * 512;              // wave-uniform LDS base (ushorts) per round

    f32x4 acc[4][4];
    #pragma unroll
    for (int i = 0; i < 4; i++)
        #pragma unroll
        for (int j = 0; j < 4; j++)
            acc[i][j] = (f32x4){0.f, 0.f, 0.f, 0.f};

    const size_t abase = (size_t)(m0 + srow) * KDIM + schunk * 8;
    const size_t bbase = (size_t)(n0 + srow) * KDIM + schunk * 8;

    for (int k0 = 0; k0 < KDIM; k0 += BK) {
        #pragma unroll
        for (int r = 0; r < 4; ++r)
            gload_lds16(A + abase + (size_t)r * 32 * KDIM + k0, &As[r * 2048 + wbase]);
        #pragma unroll
        for (int r = 0; r < 4; ++r)
            gload_lds16(Bt + bbase + (size_t)r * 32 * KDIM + k0, &Bs[r * 2048 + wbase]);

        __syncthreads();

        #pragma unroll
        for (int kk = 0; kk < BK; kk += 32) {
            // want global chunk c = kk/8 + (lane>>4); stored at slot c ^ (m&7), m&7 == lane&7
            const int soff = ((((kk >> 3) + (lane >> 4)) ^ (lane & 7)) * 8);
            bf16x8 a[4], b[4];
            #pragma unroll
            for (int i = 0; i < 4; i++)
                a[i] = *(const bf16x8*)&As[(wm + i * 16 + lrow) * BK + soff];
            #pragma unroll
            for (int j = 0; j < 4; j++)
                b[j] = *(const bf16x8*)&Bs[(wn + j * 16 + lrow) * BK + soff];
            #pragma unroll
            for (int i = 0; i < 4; i++)
                #pragma unroll
                for (int j = 0; j < 4; j++)
                    acc[i][j] = __builtin_amdgcn_mfma_f32_16x16x32_bf16(a[i], b[j], acc[i][j], 0, 0, 0);
        }

        __syncthreads();
    }

    const int crow = (lane >> 4) * 4;
    const int ccol = lane & 15;
    #pragma unroll
    for (int i = 0; i < 4; i++) {
        #pragma unroll
        for (int j = 0; j < 4; j++) {
            const int m = m0 + wm + i * 16 + crow;
            const int n = n0 + wn + j * 16 + ccol;
            #pragma unroll
            for (int r = 0; r < 4; ++r)
                out[(size_t)(m + r) * 1024 + n] = acc[i][j][r];
        }
    }
}

// ---- fallback: round-1 fused kernel (used only if ws too small) ----
#define LDK 72
__global__ __launch_bounds__(256, 2)
void taylor_gemm(const float* __restrict__ x, const float* __restrict__ trp,
                 const float* __restrict__ coef, float* __restrict__ out)
{
    __shared__ unsigned short As[BM * LDK];
    __shared__ unsigned short Bs[BN * LDK];

    const int t  = threadIdx.x;
    const int m0 = blockIdx.x * BM;
    const int n0 = blockIdx.y * BN;
    const float tr = trp[0];

    const int w    = t >> 6;
    const int lane = t & 63;
    const int wm   = (w >> 1) * 64;
    const int wn   = (w & 1) * 64;
    const int lrow = lane & 15;
    const int kq   = (lane >> 4) * 8;

    f32x4 acc[4][4];
    #pragma unroll
    for (int i = 0; i < 4; i++)
        #pragma unroll
        for (int j = 0; j < 4; j++)
            acc[i][j] = (f32x4){0.f, 0.f, 0.f, 0.f};

    const int bcol  = t & 15;
    const int brow0 = t >> 4;
    const int acol  = t & 7;
    const int arow0 = t >> 3;

    for (int k0 = 0; k0 < KDIM; k0 += BK) {
        const int i0 = k0 >> 3;
        #pragma unroll
        for (int r = 0; r < 8; ++r) {
            const int row = brow0 + r * 16;
            const float4 v = *(const float4*)(coef + (size_t)(n0 + row) * KDIM + k0 + bcol * 4);
            bf16x4 pk;
            pk[0] = (short)f2bf(v.x); pk[1] = (short)f2bf(v.y);
            pk[2] = (short)f2bf(v.z); pk[3] = (short)f2bf(v.w);
            *(bf16x4*)&Bs[row * LDK + bcol * 4] = pk;
        }
        #pragma unroll
        for (int r = 0; r < 4; ++r) {
            const int row = arow0 + r * 32;
            const float xv = x[(size_t)(m0 + row) * 1024 + i0 + acol];
            const float e  = __expf(2.0f * tr * xv);
            const float tt = 1.0f - 2.0f / (e + 1.0f);
            bf16x8 pk;
            float p = 1.0f;
            #pragma unroll
            for (int k = 0; k < 8; ++k) { pk[k] = (short)f2bf(p); p *= tt; }
            *(bf16x8*)&As[row * LDK + acol * 8] = pk;
        }
        __syncthreads();
        #pragma unroll
        for (int kk = 0; kk < BK; kk += 32) {
            bf16x8 a[4], b[4];
            #pragma unroll
            for (int i = 0; i < 4; i++)
                a[i] = *(const bf16x8*)&As[(wm + i * 16 + lrow) * LDK + kk + kq];
            #pragma unroll
            for (int j = 0; j < 4; j++)
                b[j] = *(const bf16x8*)&Bs[(wn + j * 16 + lrow) * LDK + kk + kq];
            #pragma unroll
            for (int i = 0; i < 4; i++)
                #pragma unroll
                for (int j = 0; j < 4; j++)
                    acc[i][j] = __builtin_amdgcn_mfma_f32_16x16x32_bf16(a[i], b[j], acc[i][j], 0, 0, 0);
        }
        __syncthreads();
    }

    const int crow = (lane >> 4) * 4;
    const int ccol = lane & 15;
    #pragma unroll
    for (int i = 0; i < 4; i++) {
        #pragma unroll
        for (int j = 0; j < 4; j++) {
            const int m = m0 + wm + i * 16 + crow;
            const int n = n0 + wn + j * 16 + ccol;
            #pragma unroll
            for (int r = 0; r < 4; ++r)
                out[(size_t)(m + r) * 1024 + n] = acc[i][j][r];
        }
    }
}

extern "C" void kernel_launch(void* const* d_in, const int* in_sizes, int n_in,
                              void* d_out, int out_size, void* d_ws, size_t ws_size,
                              hipStream_t stream) {
    const float* x    = (const float*)d_in[0];
    const float* trp  = (const float*)d_in[1];
    const float* coef = (const float*)d_in[2];
    float* out = (float*)d_out;

    const size_t COEF_BYTES = (size_t)1024 * KDIM * 2;            // 16 MiB
    const size_t A_BYTES    = (size_t)8192 * KDIM * 2;            // 128 MiB
    dim3 block(256);

    if (ws_size >= COEF_BYTES + A_BYTES) {
        unsigned short* coef_bf = (unsigned short*)d_ws;
        unsigned short* A_bf    = (unsigned short*)((char*)d_ws + COEF_BYTES);

        prep<<<dim3(COEF_BLOCKS + TANH_BLOCKS), block, 0, stream>>>(
            x, trp, (const float4*)coef, (bf16x4*)coef_bf, (bf16x8*)A_bf);
        gemm_bt<<<dim3(8192 / BM, 1024 / BN), block, 0, stream>>>(
            A_bf, coef_bf, out);
    } else {
        taylor_gemm<<<dim3(8192 / BM, 1024 / BN), block, 0, stream>>>(x, trp, coef, out);
    }
}